// Round 13
// baseline (171.852 us; speedup 1.0000x reference)
//
#include <hip/hip_runtime.h>

// Problem: B=8, S=2048, H=1024, D=64. fp32 in, fp32 out.
// out = softmax_causal(q k^T) / sqrt(H) @ v   (softmax FIRST, then /32)

typedef float     f32x4 __attribute__((ext_vector_type(4)));
typedef _Float16  f16x8 __attribute__((ext_vector_type(8)));
typedef _Float16  f16x4 __attribute__((ext_vector_type(4)));

// ---------------------------------------------------------------------------
// Kernel 1: pack W{q,k,v} into MFMA B-fragment order (f16) via LDS transpose.
__global__ __launch_bounds__(256) void wt_prep(const float* __restrict__ Wq,
                                               const float* __restrict__ Wk,
                                               const float* __restrict__ Wv,
                                               _Float16* __restrict__ WtF) {
  const int w  = blockIdx.x >> 4;              // which W
  const int kt = blockIdx.x & 15;              // k-tile of 64
  const float* src = (w == 0) ? Wq : (w == 1 ? Wk : Wv);
  __shared__ _Float16 ls[64][72];              // [local k][n], padded
  const int t = threadIdx.x;
  {
    int rr = t >> 4;                           // 0..15
    int c4 = (t & 15) * 4;
    #pragma unroll
    for (int ri = 0; ri < 4; ++ri) {
      int k = rr + ri * 16;                    // local k 0..63
      f32x4 f = *(const f32x4*)&src[(size_t)(kt * 64 + k) * 64 + c4];
      #pragma unroll
      for (int j = 0; j < 4; ++j) ls[k][c4 + j] = (_Float16)f[j];
    }
  }
  __syncthreads();
  const int lane = t & 63, l16 = lane & 15, quad = lane >> 4;
  #pragma unroll
  for (int h = 0; h < 2; ++h) {
    int fid     = h * 4 + (t >> 6);            // 0..7
    int kstep_l = fid >> 2;                    // 0..1
    int ntl     = fid & 3;                     // 0..3
    int nt      = w * 4 + ntl;
    int kstep   = kt * 2 + kstep_l;
    f16x8 o;
    #pragma unroll
    for (int j = 0; j < 8; ++j) o[j] = ls[kstep_l * 32 + quad * 8 + j][ntl * 16 + l16];
    *(f16x8*)&WtF[((size_t)(kstep * 12 + nt) * 64 + lane) * 8] = o;
  }
}

// ---------------------------------------------------------------------------
// Kernel 2: QKV projection -- UNCHANGED from round 12 (coalesced frag-order
// epilogue + B double-buffer; r12 showed these are neutral, kept harmless).
__global__ __launch_bounds__(512, 4) void qkv_gemm(const float* __restrict__ x,
                                                   const _Float16* __restrict__ WtF,
                                                   const float* __restrict__ bq,
                                                   const float* __restrict__ bk,
                                                   const float* __restrict__ bv,
                                                   _Float16* __restrict__ qfr,
                                                   _Float16* __restrict__ kfr,
                                                   _Float16* __restrict__ vfr) {
  __shared__ _Float16 xs[32 * 1024];           // exactly 64 KB
  const int tid  = threadIdx.x;
  const int wave = tid >> 6, lane = tid & 63;
  const int l16  = lane & 15, quad = lane >> 4;
  const int mhalf = wave >> 2;                 // 0..1
  const int ngrp  = wave & 3;                  // 0..3
  const int bid   = blockIdx.x;
  const int m0    = (((bid & 7) << 6) + (bid >> 3)) * 32;  // batch=bid&7, tile=bid>>3

  {
    int row   = tid >> 4;                      // 0..31
    int cbase = (tid & 15) * 4;
    const float* xrow = x + (size_t)(m0 + row) * 1024;
    int key = row & 7;
    #pragma unroll
    for (int j = 0; j < 16; ++j) {
      int col = cbase + j * 64;
      f32x4 f = *(const f32x4*)&xrow[col];
      f16x4 hh;
      #pragma unroll
      for (int e = 0; e < 4; ++e) hh[e] = (_Float16)f[e];
      int g   = col >> 3;                      // granule index 0..127
      int sub = col & 7;                       // 0 or 4
      *(f16x4*)&xs[(size_t)row * 1024 + (size_t)((g ^ key) << 3) + sub] = hh;
    }
  }
  __syncthreads();

  f32x4 acc0 = (f32x4){0.f,0.f,0.f,0.f};
  f32x4 acc1 = (f32x4){0.f,0.f,0.f,0.f};
  f32x4 acc2 = (f32x4){0.f,0.f,0.f,0.f};

  const int arow = mhalf * 16 + l16;
  const _Float16* abase = xs + (size_t)arow * 1024;
  const int akey = arow & 7;
  const _Float16* wbase = WtF + ((size_t)(ngrp * 3) * 64 + lane) * 8;

  f16x8 bc0 = *(const f16x8*)(wbase);
  f16x8 bc1 = *(const f16x8*)(wbase + 512);
  f16x8 bc2 = *(const f16x8*)(wbase + 1024);
  #pragma unroll 2
  for (int kstep = 0; kstep < 32; ++kstep) {
    const int kn = (kstep + 1) & 31;
    const _Float16* wkn = wbase + (size_t)kn * (12 * 64 * 8);
    f16x8 bn0 = *(const f16x8*)(wkn);
    f16x8 bn1 = *(const f16x8*)(wkn + 512);
    f16x8 bn2 = *(const f16x8*)(wkn + 1024);
    f16x8 a = *(const f16x8*)(abase + (((kstep * 4 + quad) ^ akey) << 3));
    acc0 = __builtin_amdgcn_mfma_f32_16x16x32_f16(a, bc0, acc0, 0, 0, 0);
    acc1 = __builtin_amdgcn_mfma_f32_16x16x32_f16(a, bc1, acc1, 0, 0, 0);
    acc2 = __builtin_amdgcn_mfma_f32_16x16x32_f16(a, bc2, acc2, 0, 0, 0);
    bc0 = bn0; bc1 = bn1; bc2 = bn2;
  }

  __syncthreads();
  _Float16 (*ls)[200] = (_Float16 (*)[200])xs; // 32 x 200 f16 = 12.8 KB
  {
    f32x4 accs[3] = {acc0, acc1, acc2};
    #pragma unroll
    for (int i = 0; i < 3; ++i) {
      int nt  = ngrp * 3 + i;
      int col = nt * 16 + l16;
      float bias = (nt < 4) ? bq[col] : (nt < 8) ? bk[col - 64] : bv[col - 128];
      #pragma unroll
      for (int r = 0; r < 4; ++r)
        ls[mhalf * 16 + quad * 4 + r][col] = (_Float16)(accs[i][r] + bias);
    }
  }
  __syncthreads();
  {
    const int batch = m0 >> 11;
    const int s0    = m0 & 2047;               // multiple of 32
    const int qt0   = s0 >> 4;
    {
      const int f   = wave;
      const int qtl = (f >> 1) & 1, h = f & 1;
      const int cb  = (f >= 4 ? 64 : 0) + h * 32 + quad * 8;
      f16x8 v = *(const f16x8*)&ls[qtl * 16 + l16][cb];
      _Float16* dst = (f >= 4 ? kfr : qfr)
          + ((size_t)((batch * 128 + qt0 + qtl) * 2 + h)) * 512 + lane * 8;
      *(f16x8*)dst = v;
    }
    if (wave < 4) {
      const int dt = wave;
      f16x8 v;
      #pragma unroll
      for (int j = 0; j < 8; ++j) v[j] = ls[quad * 8 + j][128 + dt * 16 + l16];
      _Float16* dst = vfr
          + (((size_t)(batch * 64 + (s0 >> 5)) * 4 + dt)) * 512 + lane * 8;
      *(f16x8*)dst = v;
    }
  }
}

// ---------------------------------------------------------------------------
// Kernel 3: causal attention -- ROUND 13: 32 q-rows per wave (two 16-row
// sub-tiles A/B sharing ONE K/V stream) -> K/V L2 traffic per unit work
// HALVED (~270 -> ~135 MB) and per-tile overheads (softmax shuffles, mask,
// P roundtrip) amortized over 2x MFMA work. Structure otherwise = r11:
// 512 blocks x 4 waves = 2048 waves = 2/SIMD all-resident; complementary
// 32-row tile pairing (p32, 63-p32) for uniform blocks; per-wave contiguous
// kv-half; register double-buffer pipeline with post-LOADT sched_barriers.
// Per-tile asm lgkm fence + sched_barrier REMOVED (plain-C++ LDS deps; m141:
// hard order-pinning defeats the scheduler). In-block 2-way LSE merge per
// sub-tile. VGPR peak ~233 < 256 cap at (256,2): no spill.
__global__ __launch_bounds__(256, 2) void attn(const _Float16* __restrict__ qfr,
                                               const _Float16* __restrict__ kfr,
                                               const _Float16* __restrict__ vfr,
                                               float* __restrict__ out) {
  const int blk  = blockIdx.x;
  const int p32  = blk >> 3;                   // 0..63
  const int b    = blk & 7;                    // batch == writer XCD slot
  const int tid  = threadIdx.x;
  const int w    = tid >> 6, lane = tid & 63;
  const int l16  = lane & 15, quad = lane >> 4;
  const int whichq = w >> 1;                   // 0: tile p32, 1: tile 63-p32
  const int half   = w & 1;                    // kv-half within the tile
  const int t32  = whichq ? (63 - p32) : p32;  // 32-row q-tile index
  const int q0   = t32 * 32;
  const int nt   = (t32 >> 1) + 1;             // kv tiles of 64 covering q0+32
  const int nh0  = (nt + 1) >> 1;
  const int t0   = half ? nh0 : 0;
  const int t1   = half ? nt : nh0;
  const int qrA  = q0 + l16;                   // sub-tile A rows q0..q0+15
  const int qrB  = q0 + 16 + l16;              // sub-tile B rows q0+16..q0+31

  // per-wave: P (f16[16][72], 2304B) overlays obA; obB at +4352
  __shared__ __align__(16) unsigned char sbuf[4][8704];
  __shared__ float mlb[4][2][2][16];           // [wave][sub][m/l][row]
  _Float16 (*Pw)[72] = (_Float16 (*)[72])&sbuf[w][0];

  // frag-order bases (all loads = base + lane*8, 1KB wave-burst)
  const _Float16* qba = qfr + ((size_t)(b * 128 + t32 * 2) * 2) * 512 + lane * 8;
  const _Float16* kb  = kfr + ((size_t)b * 256) * 512 + lane * 8;
  const _Float16* vb  = vfr + ((size_t)b * 256) * 512 + lane * 8;

  const f16x8 qa0 = *(const f16x8*)(qba);
  const f16x8 qa1 = *(const f16x8*)(qba + 512);
  const f16x8 qb0 = *(const f16x8*)(qba + 1024);
  const f16x8 qb1 = *(const f16x8*)(qba + 1536);

  const float L2E = 1.44269504088896340736f;
  float mA = -1e30f, lA = 0.f, mB = -1e30f, lB = 0.f;
  f32x4 oA_[4], oB_[4];
  #pragma unroll
  for (int i = 0; i < 4; ++i) {
    oA_[i] = (f32x4){0.f, 0.f, 0.f, 0.f};
    oB_[i] = (f32x4){0.f, 0.f, 0.f, 0.f};
  }

  // static double buffers (rule #20: no runtime indexing)
  f16x8 kfA[4][2], kfB[4][2], vfA[2][4], vfB[2][4];

  auto LOADT = [&](f16x8 (&kf)[4][2], f16x8 (&vf)[2][4], int t) {
    const _Float16* kp = kb + (size_t)t * 4096;
    #pragma unroll
    for (int st = 0; st < 4; ++st) {
      kf[st][0] = *(const f16x8*)(kp + st * 1024);
      kf[st][1] = *(const f16x8*)(kp + st * 1024 + 512);
    }
    const _Float16* vp = vb + (size_t)t * 4096;
    #pragma unroll
    for (int ks = 0; ks < 2; ++ks)
      #pragma unroll
      for (int dt = 0; dt < 4; ++dt)
        vf[ks][dt] = *(const f16x8*)(vp + ks * 2048 + dt * 512);
  };

  auto COMPUTE = [&](const f16x8 (&kf)[4][2], const f16x8 (&vf)[2][4], int t) {
    const int kvb = t * 64;
    // QK^T for BOTH sub-tiles off the same K frags
    f32x4 sa[4], sb[4];
    #pragma unroll
    for (int st = 0; st < 4; ++st) {
      f32x4 ca = (f32x4){0.f, 0.f, 0.f, 0.f};
      ca = __builtin_amdgcn_mfma_f32_16x16x32_f16(kf[st][0], qa0, ca, 0, 0, 0);
      ca = __builtin_amdgcn_mfma_f32_16x16x32_f16(kf[st][1], qa1, ca, 0, 0, 0);
      sa[st] = ca;
      f32x4 cb = (f32x4){0.f, 0.f, 0.f, 0.f};
      cb = __builtin_amdgcn_mfma_f32_16x16x32_f16(kf[st][0], qb0, cb, 0, 0, 0);
      cb = __builtin_amdgcn_mfma_f32_16x16x32_f16(kf[st][1], qb1, cb, 0, 0, 0);
      sb[st] = cb;
    }
    if (kvb + 63 > q0) {                       // mask sub-tile A
      #pragma unroll
      for (int st = 0; st < 4; ++st)
        #pragma unroll
        for (int r = 0; r < 4; ++r)
          if (kvb + st * 16 + quad * 4 + r > qrA) sa[st][r] = -1e30f;
    }
    if (kvb + 63 > q0 + 16) {                  // mask sub-tile B
      #pragma unroll
      for (int st = 0; st < 4; ++st)
        #pragma unroll
        for (int r = 0; r < 4; ++r)
          if (kvb + st * 16 + quad * 4 + r > qrB) sb[st][r] = -1e30f;
    }

    // ---- sub-tile A: softmax + P roundtrip + PV ----
    {
      float mx = -1e30f;
      #pragma unroll
      for (int st = 0; st < 4; ++st)
        mx = fmaxf(mx, fmaxf(fmaxf(sa[st][0], sa[st][1]), fmaxf(sa[st][2], sa[st][3])));
      mx = fmaxf(mx, __shfl_xor(mx, 16, 64));
      mx = fmaxf(mx, __shfl_xor(mx, 32, 64));
      const float mnew  = fmaxf(mA, mx);
      const float alpha = exp2f((mA - mnew) * L2E);
      mA = mnew;
      float s = 0.f;
      #pragma unroll
      for (int st = 0; st < 4; ++st) {
        #pragma unroll
        for (int r = 0; r < 4; ++r) sa[st][r] = exp2f((sa[st][r] - mA) * L2E);
        s += (sa[st][0] + sa[st][1]) + (sa[st][2] + sa[st][3]);
      }
      s += __shfl_xor(s, 16, 64);
      s += __shfl_xor(s, 32, 64);
      lA = lA * alpha + s;
      #pragma unroll
      for (int dt = 0; dt < 4; ++dt)
        #pragma unroll
        for (int r = 0; r < 4; ++r) oA_[dt][r] *= alpha;
      #pragma unroll
      for (int st = 0; st < 4; ++st) {
        f16x4 ph;
        #pragma unroll
        for (int r = 0; r < 4; ++r) ph[r] = (_Float16)sa[st][r];
        *(f16x4*)&Pw[l16][st * 16 + quad * 4] = ph;
      }
      #pragma unroll
      for (int ks = 0; ks < 2; ++ks) {
        f16x8 pf = *(const f16x8*)&Pw[l16][ks * 32 + quad * 8];
        #pragma unroll
        for (int dt = 0; dt < 4; ++dt)
          oA_[dt] = __builtin_amdgcn_mfma_f32_16x16x32_f16(vf[ks][dt], pf, oA_[dt], 0, 0, 0);
      }
    }

    // ---- sub-tile B: softmax + P roundtrip + PV ----
    {
      float mx = -1e30f;
      #pragma unroll
      for (int st = 0; st < 4; ++st)
        mx = fmaxf(mx, fmaxf(fmaxf(sb[st][0], sb[st][1]), fmaxf(sb[st][2], sb[st][3])));
      mx = fmaxf(mx, __shfl_xor(mx, 16, 64));
      mx = fmaxf(mx, __shfl_xor(mx, 32, 64));
      const float mnew  = fmaxf(mB, mx);
      const float alpha = exp2f((mB - mnew) * L2E);
      mB = mnew;
      float s = 0.f;
      #pragma unroll
      for (int st = 0; st < 4; ++st) {
        #pragma unroll
        for (int r = 0; r < 4; ++r) sb[st][r] = exp2f((sb[st][r] - mB) * L2E);
        s += (sb[st][0] + sb[st][1]) + (sb[st][2] + sb[st][3]);
      }
      s += __shfl_xor(s, 16, 64);
      s += __shfl_xor(s, 32, 64);
      lB = lB * alpha + s;
      #pragma unroll
      for (int dt = 0; dt < 4; ++dt)
        #pragma unroll
        for (int r = 0; r < 4; ++r) oB_[dt][r] *= alpha;
      #pragma unroll
      for (int st = 0; st < 4; ++st) {
        f16x4 ph;
        #pragma unroll
        for (int r = 0; r < 4; ++r) ph[r] = (_Float16)sb[st][r];
        *(f16x4*)&Pw[l16][st * 16 + quad * 4] = ph;
      }
      #pragma unroll
      for (int ks = 0; ks < 2; ++ks) {
        f16x8 pf = *(const f16x8*)&Pw[l16][ks * 32 + quad * 8];
        #pragma unroll
        for (int dt = 0; dt < 4; ++dt)
          oB_[dt] = __builtin_amdgcn_mfma_f32_16x16x32_f16(vf[ks][dt], pf, oB_[dt], 0, 0, 0);
      }
    }
  };

  // software-pipelined kv loop: load t+1 before computing t
  int t = t0;
  if (t < t1) {
    LOADT(kfA, vfA, t);
    while (t + 1 < t1) {
      LOADT(kfB, vfB, t + 1);
      __builtin_amdgcn_sched_barrier(0);
      COMPUTE(kfA, vfA, t);
      if (t + 2 < t1) {
        LOADT(kfA, vfA, t + 2);
        __builtin_amdgcn_sched_barrier(0);
      }
      COMPUTE(kfB, vfB, t + 1);
      t += 2;
    }
    if (t < t1) COMPUTE(kfA, vfA, t);
  }

  // publish per-wave partials (obA overlays Pw -- safe: last P reads done)
  {
    float (*obA)[68] = (float (*)[68])&sbuf[w][0];
    float (*obB)[68] = (float (*)[68])&sbuf[w][4352];
    #pragma unroll
    for (int dt = 0; dt < 4; ++dt) {
      *(f32x4*)&obA[l16][dt * 16 + quad * 4] = oA_[dt];
      *(f32x4*)&obB[l16][dt * 16 + quad * 4] = oB_[dt];
    }
    if (quad == 0) {
      mlb[w][0][0][l16] = mA; mlb[w][0][1][l16] = lA;
      mlb[w][1][0][l16] = mB; mlb[w][1][1][l16] = lB;
    }
  }
  __syncthreads();

  // 2-way LSE merge: grp = wave slot -> (whichq = grp>>1, sub = grp&1);
  // 64 threads per group: row = idx>>2, 16 cols starting (idx&3)*16.
  {
    const int grp = tid >> 6;
    const int idx = tid & 63;
    const int row = idx >> 2;
    const int c16 = (idx & 3) * 16;
    const int wb  = (grp >> 1) * 2;
    const int sub = grp & 1;
    const int t32g = (grp >> 1) ? (63 - p32) : p32;
    const float m0v = mlb[wb][sub][0][row], m1v = mlb[wb + 1][sub][0][row];
    const float M   = fmaxf(m0v, m1v);
    const float w0  = exp2f((m0v - M) * L2E);
    const float w1  = exp2f((m1v - M) * L2E);
    const float L   = w0 * mlb[wb][sub][1][row] + w1 * mlb[wb + 1][sub][1][row];
    const float inv = 1.0f / (L * 32.0f);      // sqrt(H)=32 applied AFTER softmax
    const float (*oX)[68] = (const float (*)[68])&sbuf[wb][sub * 4352];
    const float (*oY)[68] = (const float (*)[68])&sbuf[wb + 1][sub * 4352];
    float* dst = out + ((size_t)b * 2048 + t32g * 32 + sub * 16 + row) * 64 + c16;
    #pragma unroll
    for (int j = 0; j < 4; ++j) {
      f32x4 a  = *(const f32x4*)&oX[row][c16 + j * 4];
      f32x4 bb = *(const f32x4*)&oY[row][c16 + j * 4];
      f32x4 r;
      #pragma unroll
      for (int e = 0; e < 4; ++e) r[e] = (w0 * a[e] + w1 * bb[e]) * inv;
      *(f32x4*)&dst[j * 4] = r;
    }
  }
}

// ---------------------------------------------------------------------------
extern "C" void kernel_launch(void* const* d_in, const int* in_sizes, int n_in,
                              void* d_out, int out_size, void* d_ws, size_t ws_size,
                              hipStream_t stream) {
  const float* x  = (const float*)d_in[0];
  const float* Wq = (const float*)d_in[1];
  const float* bq = (const float*)d_in[2];
  const float* Wk = (const float*)d_in[3];
  const float* bk = (const float*)d_in[4];
  const float* Wv = (const float*)d_in[5];
  const float* bv = (const float*)d_in[6];
  float* out = (float*)d_out;

  // ws layout (f16): WtF 192*1024 | qfr 1M | kfr 1M | vfr 1M  (~6.7MB)
  _Float16* WtF = (_Float16*)d_ws;
  _Float16* qfr = WtF + 192 * 1024;
  _Float16* kfr = qfr + (size_t)8 * 128 * 2 * 512;
  _Float16* vfr = kfr + (size_t)8 * 128 * 2 * 512;

  hipLaunchKernelGGL(wt_prep,  dim3(48),  dim3(256), 0, stream, Wq, Wk, Wv, WtF);
  hipLaunchKernelGGL(qkv_gemm, dim3(512), dim3(512), 0, stream, x, WtF, bq, bk, bv, qfr, kfr, vfr);
  hipLaunchKernelGGL(attn,     dim3(512), dim3(256), 0, stream, qfr, kfr, vfr, out);
}

// Round 14
// 166.288 us; speedup vs baseline: 1.0335x; 1.0335x over previous
//
#include <hip/hip_runtime.h>

// Problem: B=8, S=2048, H=1024, D=64. fp32 in, fp32 out.
// out = softmax_causal(q k^T) / sqrt(H) @ v   (softmax FIRST, then /32)

typedef float     f32x4 __attribute__((ext_vector_type(4)));
typedef _Float16  f16x8 __attribute__((ext_vector_type(8)));
typedef _Float16  f16x4 __attribute__((ext_vector_type(4)));

// ---------------------------------------------------------------------------
// Kernel 1: pack W{q,k,v} into MFMA B-fragment order (f16) via LDS transpose.
__global__ __launch_bounds__(256) void wt_prep(const float* __restrict__ Wq,
                                               const float* __restrict__ Wk,
                                               const float* __restrict__ Wv,
                                               _Float16* __restrict__ WtF) {
  const int w  = blockIdx.x >> 4;              // which W
  const int kt = blockIdx.x & 15;              // k-tile of 64
  const float* src = (w == 0) ? Wq : (w == 1 ? Wk : Wv);
  __shared__ _Float16 ls[64][72];              // [local k][n], padded
  const int t = threadIdx.x;
  {
    int rr = t >> 4;                           // 0..15
    int c4 = (t & 15) * 4;
    #pragma unroll
    for (int ri = 0; ri < 4; ++ri) {
      int k = rr + ri * 16;                    // local k 0..63
      f32x4 f = *(const f32x4*)&src[(size_t)(kt * 64 + k) * 64 + c4];
      #pragma unroll
      for (int j = 0; j < 4; ++j) ls[k][c4 + j] = (_Float16)f[j];
    }
  }
  __syncthreads();
  const int lane = t & 63, l16 = lane & 15, quad = lane >> 4;
  #pragma unroll
  for (int h = 0; h < 2; ++h) {
    int fid     = h * 4 + (t >> 6);            // 0..7
    int kstep_l = fid >> 2;                    // 0..1
    int ntl     = fid & 3;                     // 0..3
    int nt      = w * 4 + ntl;
    int kstep   = kt * 2 + kstep_l;
    f16x8 o;
    #pragma unroll
    for (int j = 0; j < 8; ++j) o[j] = ls[kstep_l * 32 + quad * 8 + j][ntl * 16 + l16];
    *(f16x8*)&WtF[((size_t)(kstep * 12 + nt) * 64 + lane) * 8] = o;
  }
}

// ---------------------------------------------------------------------------
// Kernel 2: QKV projection -- ROUND 14 INSTRUMENTED: K-loop repeated 4x
// (#pragma unroll 1 rep loop; acc accumulates exactly 4x the true value --
// live dependency chain, no DCE -- epilogue scales by 0.25f, bitwise-exact).
// Purpose: push qkv above the 41us fill threshold so rocprof top-5 shows its
// TRUE counters (never measured -- always hidden below the fills). Algebra:
// Kloop = (total_r14 - 135.1)/3; qkv_r12 = qkv_dispatch - 3*Kloop.
__global__ __launch_bounds__(512, 4) void qkv_gemm(const float* __restrict__ x,
                                                   const _Float16* __restrict__ WtF,
                                                   const float* __restrict__ bq,
                                                   const float* __restrict__ bk,
                                                   const float* __restrict__ bv,
                                                   _Float16* __restrict__ qfr,
                                                   _Float16* __restrict__ kfr,
                                                   _Float16* __restrict__ vfr) {
  __shared__ _Float16 xs[32 * 1024];           // exactly 64 KB
  const int tid  = threadIdx.x;
  const int wave = tid >> 6, lane = tid & 63;
  const int l16  = lane & 15, quad = lane >> 4;
  const int mhalf = wave >> 2;                 // 0..1
  const int ngrp  = wave & 3;                  // 0..3
  const int bid   = blockIdx.x;
  const int m0    = (((bid & 7) << 6) + (bid >> 3)) * 32;  // batch=bid&7, tile=bid>>3

  {
    int row   = tid >> 4;                      // 0..31
    int cbase = (tid & 15) * 4;
    const float* xrow = x + (size_t)(m0 + row) * 1024;
    int key = row & 7;
    #pragma unroll
    for (int j = 0; j < 16; ++j) {
      int col = cbase + j * 64;
      f32x4 f = *(const f32x4*)&xrow[col];
      f16x4 hh;
      #pragma unroll
      for (int e = 0; e < 4; ++e) hh[e] = (_Float16)f[e];
      int g   = col >> 3;                      // granule index 0..127
      int sub = col & 7;                       // 0 or 4
      *(f16x4*)&xs[(size_t)row * 1024 + (size_t)((g ^ key) << 3) + sub] = hh;
    }
  }
  __syncthreads();

  f32x4 acc0 = (f32x4){0.f,0.f,0.f,0.f};
  f32x4 acc1 = (f32x4){0.f,0.f,0.f,0.f};
  f32x4 acc2 = (f32x4){0.f,0.f,0.f,0.f};

  const int arow = mhalf * 16 + l16;
  const _Float16* abase = xs + (size_t)arow * 1024;
  const int akey = arow & 7;
  const _Float16* wbase = WtF + ((size_t)(ngrp * 3) * 64 + lane) * 8;

  #pragma unroll 1
  for (int rep = 0; rep < 4; ++rep) {          // 4x instrumentation repeat
    f16x8 bc0 = *(const f16x8*)(wbase);
    f16x8 bc1 = *(const f16x8*)(wbase + 512);
    f16x8 bc2 = *(const f16x8*)(wbase + 1024);
    #pragma unroll 2
    for (int kstep = 0; kstep < 32; ++kstep) {
      const int kn = (kstep + 1) & 31;
      const _Float16* wkn = wbase + (size_t)kn * (12 * 64 * 8);
      f16x8 bn0 = *(const f16x8*)(wkn);
      f16x8 bn1 = *(const f16x8*)(wkn + 512);
      f16x8 bn2 = *(const f16x8*)(wkn + 1024);
      f16x8 a = *(const f16x8*)(abase + (((kstep * 4 + quad) ^ akey) << 3));
      acc0 = __builtin_amdgcn_mfma_f32_16x16x32_f16(a, bc0, acc0, 0, 0, 0);
      acc1 = __builtin_amdgcn_mfma_f32_16x16x32_f16(a, bc1, acc1, 0, 0, 0);
      acc2 = __builtin_amdgcn_mfma_f32_16x16x32_f16(a, bc2, acc2, 0, 0, 0);
      bc0 = bn0; bc1 = bn1; bc2 = bn2;
    }
  }

  __syncthreads();
  _Float16 (*ls)[200] = (_Float16 (*)[200])xs; // 32 x 200 f16 = 12.8 KB
  {
    f32x4 accs[3] = {acc0, acc1, acc2};
    #pragma unroll
    for (int i = 0; i < 3; ++i) {
      int nt  = ngrp * 3 + i;
      int col = nt * 16 + l16;
      float bias = (nt < 4) ? bq[col] : (nt < 8) ? bk[col - 64] : bv[col - 128];
      #pragma unroll
      for (int r = 0; r < 4; ++r)
        ls[mhalf * 16 + quad * 4 + r][col] = (_Float16)(accs[i][r] * 0.25f + bias);
    }
  }
  __syncthreads();
  {
    const int batch = m0 >> 11;
    const int s0    = m0 & 2047;               // multiple of 32
    const int qt0   = s0 >> 4;
    {
      const int f   = wave;
      const int qtl = (f >> 1) & 1, h = f & 1;
      const int cb  = (f >= 4 ? 64 : 0) + h * 32 + quad * 8;
      f16x8 v = *(const f16x8*)&ls[qtl * 16 + l16][cb];
      _Float16* dst = (f >= 4 ? kfr : qfr)
          + ((size_t)((batch * 128 + qt0 + qtl) * 2 + h)) * 512 + lane * 8;
      *(f16x8*)dst = v;
    }
    if (wave < 4) {
      const int dt = wave;
      f16x8 v;
      #pragma unroll
      for (int j = 0; j < 8; ++j) v[j] = ls[quad * 8 + j][128 + dt * 16 + l16];
      _Float16* dst = vfr
          + (((size_t)(batch * 64 + (s0 >> 5)) * 4 + dt)) * 512 + lane * 8;
      *(f16x8*)dst = v;
    }
  }
}

// ---------------------------------------------------------------------------
// Kernel 3: causal attention -- REVERTED to the r11/r12 known-good version
// (looped per-wave flash, 16 q-rows/wave, register double-buffer, frag-order
// 1KB-burst loads, online softmax, in-block 2-way LSE merge). r13's 32-row
// variant hit the 128-VGPR wall and spilled (70MB scratch, 62us).
__global__ __launch_bounds__(256, 2) void attn(const _Float16* __restrict__ qfr,
                                               const _Float16* __restrict__ kfr,
                                               const _Float16* __restrict__ vfr,
                                               float* __restrict__ out) {
  const int blk  = blockIdx.x;
  const int pair = blk >> 3;                   // 0..63
  const int b    = blk & 7;                    // batch == writer XCD slot
  const int tid  = threadIdx.x;
  const int w    = tid >> 6, lane = tid & 63;
  const int l16  = lane & 15, quad = lane >> 4;
  const int whichq = w >> 1;                   // 0: qtA, 1: qtB
  const int half   = w & 1;                    // kv-half within the q-tile
  const int qt   = whichq ? (127 - pair) : pair;
  const int q0   = qt * 16;
  const int qrow = q0 + l16;
  const int nt   = (qt >> 2) + 1;              // kv tiles of 64 (ceil((q0+16)/64))
  const int nh0  = (nt + 1) >> 1;
  const int t0   = half ? nh0 : 0;
  const int t1   = half ? nt : nh0;

  // per-wave P (f16[16][72], 2304B) overlaid with ob (f32[16][68], 4352B)
  __shared__ __align__(16) unsigned char sbuf[4][4352];
  __shared__ float mlb[4][2][16];
  _Float16 (*Pw)[72]  = (_Float16 (*)[72])&sbuf[w][0];
  float    (*obw)[68] = (float    (*)[68])&sbuf[w][0];

  // frag-order bases: every load is base + lane*8 (1KB wave-burst)
  const _Float16* qb = qfr + ((size_t)(b * 128 + qt) * 2) * 512 + lane * 8;
  const _Float16* kb = kfr + ((size_t)b * 128 * 2) * 512 + lane * 8;
  const _Float16* vb = vfr + ((size_t)b * 64 * 4) * 512 + lane * 8;

  const f16x8 qf0 = *(const f16x8*)(qb);
  const f16x8 qf1 = *(const f16x8*)(qb + 512);

  const float L2E = 1.44269504088896340736f;
  float m = -1e30f, l = 0.f;
  f32x4 o_[4];
  #pragma unroll
  for (int i = 0; i < 4; ++i) o_[i] = (f32x4){0.f, 0.f, 0.f, 0.f};

  // static double buffers (rule #20: no runtime indexing)
  f16x8 kfA[4][2], kfB[4][2], vfA[2][4], vfB[2][4];

  auto LOADT = [&](f16x8 (&kf)[4][2], f16x8 (&vf)[2][4], int t) {
    const _Float16* kp = kb + (size_t)t * 4096;
    #pragma unroll
    for (int st = 0; st < 4; ++st) {
      kf[st][0] = *(const f16x8*)(kp + st * 1024);
      kf[st][1] = *(const f16x8*)(kp + st * 1024 + 512);
    }
    const _Float16* vp = vb + (size_t)t * 4096;
    #pragma unroll
    for (int ks = 0; ks < 2; ++ks)
      #pragma unroll
      for (int dt = 0; dt < 4; ++dt)
        vf[ks][dt] = *(const f16x8*)(vp + ks * 2048 + dt * 512);
  };

  auto COMPUTE = [&](const f16x8 (&kf)[4][2], const f16x8 (&vf)[2][4], int t) {
    const int kvb = t * 64;
    f32x4 sc[4];
    #pragma unroll
    for (int st = 0; st < 4; ++st) {
      f32x4 cc = (f32x4){0.f, 0.f, 0.f, 0.f};
      cc = __builtin_amdgcn_mfma_f32_16x16x32_f16(kf[st][0], qf0, cc, 0, 0, 0);
      cc = __builtin_amdgcn_mfma_f32_16x16x32_f16(kf[st][1], qf1, cc, 0, 0, 0);
      sc[st] = cc;
    }
    if (kvb + 63 > q0) {                       // diagonal tile: causal mask
      #pragma unroll
      for (int st = 0; st < 4; ++st)
        #pragma unroll
        for (int r = 0; r < 4; ++r)
          if (kvb + st * 16 + quad * 4 + r > qrow) sc[st][r] = -1e30f;
    }
    float mx = -1e30f;
    #pragma unroll
    for (int st = 0; st < 4; ++st)
      mx = fmaxf(mx, fmaxf(fmaxf(sc[st][0], sc[st][1]), fmaxf(sc[st][2], sc[st][3])));
    mx = fmaxf(mx, __shfl_xor(mx, 16, 64));
    mx = fmaxf(mx, __shfl_xor(mx, 32, 64));
    const float mnew  = fmaxf(m, mx);
    const float alpha = exp2f((m - mnew) * L2E);
    m = mnew;
    float s = 0.f;
    #pragma unroll
    for (int st = 0; st < 4; ++st) {
      #pragma unroll
      for (int r = 0; r < 4; ++r) sc[st][r] = exp2f((sc[st][r] - m) * L2E);
      s += (sc[st][0] + sc[st][1]) + (sc[st][2] + sc[st][3]);
    }
    s += __shfl_xor(s, 16, 64);
    s += __shfl_xor(s, 32, 64);
    l = l * alpha + s;
    #pragma unroll
    for (int dt = 0; dt < 4; ++dt)
      #pragma unroll
      for (int r = 0; r < 4; ++r) o_[dt][r] *= alpha;
    #pragma unroll
    for (int st = 0; st < 4; ++st) {
      f16x4 ph;
      #pragma unroll
      for (int r = 0; r < 4; ++r) ph[r] = (_Float16)sc[st][r];
      *(f16x4*)&Pw[l16][st * 16 + quad * 4] = ph;
    }
    asm volatile("s_waitcnt lgkmcnt(0)" ::: "memory");
    __builtin_amdgcn_sched_barrier(0);
    #pragma unroll
    for (int ks = 0; ks < 2; ++ks) {
      f16x8 pf = *(const f16x8*)&Pw[l16][ks * 32 + quad * 8];
      #pragma unroll
      for (int dt = 0; dt < 4; ++dt)
        o_[dt] = __builtin_amdgcn_mfma_f32_16x16x32_f16(vf[ks][dt], pf, o_[dt], 0, 0, 0);
    }
  };

  // software-pipelined kv loop: load t+1 before computing t
  int t = t0;
  if (t < t1) {
    LOADT(kfA, vfA, t);
    while (t + 1 < t1) {
      LOADT(kfB, vfB, t + 1);
      __builtin_amdgcn_sched_barrier(0);
      COMPUTE(kfA, vfA, t);
      if (t + 2 < t1) {
        LOADT(kfA, vfA, t + 2);
        __builtin_amdgcn_sched_barrier(0);
      }
      COMPUTE(kfB, vfB, t + 1);
      t += 2;
    }
    if (t < t1) COMPUTE(kfA, vfA, t);
  }

  // publish per-wave partials: obw[q][d] = O[d][q]^T, (m,l) per q-row
  #pragma unroll
  for (int dt = 0; dt < 4; ++dt)
    *(f32x4*)&obw[l16][dt * 16 + quad * 4] = o_[dt];
  if (quad == 0) {
    mlb[w][0][l16] = m;
    mlb[w][1][l16] = l;
  }
  __syncthreads();

  // 2-way LSE merge per q-tile: waves (0,1) -> qtA, (2,3) -> qtB
  {
    const int grp = tid >> 7;                  // 0: qtA, 1: qtB
    const int idx = tid & 127;
    const int row = idx >> 3;
    const int c8  = (idx & 7) * 8;
    const int wb  = grp * 2;
    const int qtg = grp ? (127 - pair) : pair;
    const float m0v = mlb[wb][0][row], m1v = mlb[wb + 1][0][row];
    const float M   = fmaxf(m0v, m1v);
    const float w0  = exp2f((m0v - M) * L2E);
    const float w1  = exp2f((m1v - M) * L2E);
    const float L   = w0 * mlb[wb][1][row] + w1 * mlb[wb + 1][1][row];
    const float inv = 1.0f / (L * 32.0f);      // sqrt(H)=32 applied AFTER softmax
    const float (*oA)[68] = (const float (*)[68])&sbuf[wb][0];
    const float (*oB)[68] = (const float (*)[68])&sbuf[wb + 1][0];
    float* dst = out + ((size_t)b * 2048 + qtg * 16 + row) * 64 + c8;
    #pragma unroll
    for (int j = 0; j < 2; ++j) {
      f32x4 a = *(const f32x4*)&oA[row][c8 + j * 4];
      f32x4 bb = *(const f32x4*)&oB[row][c8 + j * 4];
      f32x4 r;
      #pragma unroll
      for (int e = 0; e < 4; ++e) r[e] = (w0 * a[e] + w1 * bb[e]) * inv;
      *(f32x4*)&dst[j * 4] = r;
    }
  }
}

// ---------------------------------------------------------------------------
extern "C" void kernel_launch(void* const* d_in, const int* in_sizes, int n_in,
                              void* d_out, int out_size, void* d_ws, size_t ws_size,
                              hipStream_t stream) {
  const float* x  = (const float*)d_in[0];
  const float* Wq = (const float*)d_in[1];
  const float* bq = (const float*)d_in[2];
  const float* Wk = (const float*)d_in[3];
  const float* bk = (const float*)d_in[4];
  const float* Wv = (const float*)d_in[5];
  const float* bv = (const float*)d_in[6];
  float* out = (float*)d_out;

  // ws layout (f16): WtF 192*1024 | qfr 1M | kfr 1M | vfr 1M  (~6.7MB)
  _Float16* WtF = (_Float16*)d_ws;
  _Float16* qfr = WtF + 192 * 1024;
  _Float16* kfr = qfr + (size_t)8 * 128 * 2 * 512;
  _Float16* vfr = kfr + (size_t)8 * 128 * 2 * 512;

  hipLaunchKernelGGL(wt_prep,  dim3(48),  dim3(256), 0, stream, Wq, Wk, Wv, WtF);
  hipLaunchKernelGGL(qkv_gemm, dim3(512), dim3(512), 0, stream, x, WtF, bq, bk, bv, qfr, kfr, vfr);
  hipLaunchKernelGGL(attn,     dim3(512), dim3(256), 0, stream, qfr, kfr, vfr, out);
}